// Round 12
// baseline (31.839 us; speedup 1.0000x reference)
//
#include <hip/hip_runtime.h>
#include <hip/hip_bf16.h>

constexpr int B = 1024, S = 128, E = 256, C = 256, T = 12;

typedef short s8v __attribute__((ext_vector_type(8)));   // 8 x bf16 bits
typedef float f4v __attribute__((ext_vector_type(4)));

__device__ __forceinline__ short f2bf(float f) {
    unsigned u = __builtin_bit_cast(unsigned, f);
    return (short)((u + 0x7FFFu + ((u >> 16) & 1u)) >> 16);
}
__device__ __forceinline__ s8v cvt8(float4 a, float4 b) {
    s8v o;
    o[0] = f2bf(a.x); o[1] = f2bf(a.y); o[2] = f2bf(a.z); o[3] = f2bf(a.w);
    o[4] = f2bf(b.x); o[5] = f2bf(b.y); o[6] = f2bf(b.z); o[7] = f2bf(b.w);
    return o;
}

// ---------------- Kernel 1: pred[t] = c_last @ Wk_w[t]^T (bias cancels in log-softmax) ----
// R7-proven: 128x128 tiles, 512 threads, f32 in (cvt in staging). Zero-inits rowsum and out.
__global__ __launch_bounds__(512) void pred_kernel(
    const float* __restrict__ c, const float* __restrict__ wkw,
    const int* __restrict__ tsp, short* __restrict__ pred,
    float* __restrict__ rowsum, float* __restrict__ out)
{
    // zero rowsum (12288 floats) + out
    {
        int gi = blockIdx.x * 512 + threadIdx.x;
        if (gi < T * B) rowsum[gi] = 0.0f;
        if (gi == 0) out[0] = 0.0f;
    }
    // bijective XCD swizzle: 192 blocks = 8 xcd * 24; (t,eb) pairs clustered per xcd
    int wgid = blockIdx.x;
    int xcd = wgid & 7, q = wgid >> 3;          // q in 0..23
    int pr = xcd * 3 + (q >> 3);                // 0..23 : (t,eb) pair id
    int bb = q & 7;                              // b-row block (128 rows)
    int t = pr >> 1, eb = pr & 1;                // e-col block (128 cols)
    const int ts = tsp[0];

    __shared__ __align__(16) short AS[128 * 256];   // c_last tile (bf16), 64 KB
    __shared__ __align__(16) short BS[128 * 256];   // wkw tile (bf16), 64 KB
    const int tid = threadIdx.x;

    #pragma unroll
    for (int it = 0; it < 8; ++it) {
        int idx = it * 512 + tid;
        int r = idx >> 5, s = idx & 31;
        const float4* pa = reinterpret_cast<const float4*>(
            c + (size_t)(bb * 128 + r) * S * C + (size_t)ts * C + s * 8);
        *reinterpret_cast<s8v*>(AS + r * 256 + ((s ^ (r & 7)) * 8)) = cvt8(pa[0], pa[1]);
        const float4* pb = reinterpret_cast<const float4*>(
            wkw + ((size_t)t * E + eb * 128 + r) * 256 + s * 8);
        *reinterpret_cast<s8v*>(BS + r * 256 + ((s ^ (r & 7)) * 8)) = cvt8(pb[0], pb[1]);
    }
    __syncthreads();

    const int wv = tid >> 6, ln = tid & 63;
    const int wr = wv >> 2, wc = wv & 3;        // 2 row-groups(64) x 4 col-groups(32)
    const int lr = ln & 15, lg = ln >> 4;
    f4v acc[4][2] = {};

    #pragma unroll
    for (int kk = 0; kk < 8; ++kk) {
        int slot = kk * 4 + lg;
        s8v a[4], b[2];
        #pragma unroll
        for (int m = 0; m < 4; ++m) {
            int r = wr * 64 + m * 16 + lr;
            a[m] = *reinterpret_cast<const s8v*>(AS + r * 256 + ((slot ^ (r & 7)) * 8));
        }
        #pragma unroll
        for (int n = 0; n < 2; ++n) {
            int r = wc * 32 + n * 16 + lr;
            b[n] = *reinterpret_cast<const s8v*>(BS + r * 256 + ((slot ^ (r & 7)) * 8));
        }
        #pragma unroll
        for (int m = 0; m < 4; ++m)
            #pragma unroll
            for (int n = 0; n < 2; ++n)
                acc[m][n] = __builtin_amdgcn_mfma_f32_16x16x32_bf16(a[m], b[n], acc[m][n], 0, 0, 0);
    }

    #pragma unroll
    for (int m = 0; m < 4; ++m)
        #pragma unroll
        for (int n = 0; n < 2; ++n)
            #pragma unroll
            for (int i = 0; i < 4; ++i) {
                int bg = bb * 128 + wr * 64 + m * 16 + lg * 4 + i;   // b row
                int eg = eb * 128 + wc * 32 + n * 16 + lr;           // e col
                pred[(size_t)t * B * E + (size_t)bg * E + eg] = f2bf(acc[m][n][i]);
            }
}

// ---------------- Kernel 2: scores tile + exp-sum partials (no-max) + diag ----------------
// R7 structure + FULL upfront register prefetch: all 8 pred-eighths (16 x 16B/thread) are
// loaded in the prologue; the K-loop has ZERO global loads (compiler emits counted vmcnt
// before each staged LDS write). Conflict-free staging indexing (R11). Last barrier dropped.
__global__ __launch_bounds__(512) void score_kernel(
    const float* __restrict__ z, const short* __restrict__ pred,
    const int* __restrict__ tsp,
    float* __restrict__ rowsum, float* __restrict__ diag_g)
{
    // bijective swizzle: 768 = 8 xcd * 96; (ci,t) clustered per xcd (pred chunk L2-local)
    int wgid = blockIdx.x;
    int xcd = wgid & 7, q = wgid >> 3;           // q in 0..95
    int pairid = xcd * 6 + (q >> 4);             // 0..47
    int rb = q & 15;                              // enc row-block (64 rows)
    int t = pairid >> 2, ci = pairid & 3;         // col chunk (256 cols)
    const int ts = tsp[0];

    __shared__ __align__(16) char SM[65536];
    short* encS = reinterpret_cast<short*>(SM);              // 64x256 bf16 = 32 KB
    short* buf0 = reinterpret_cast<short*>(SM + 32768);      // pred eighth [4][256][8] = 16 KB
    short* buf1 = reinterpret_cast<short*>(SM + 49152);      // 16 KB

    const int tid = threadIdx.x;
    const short* pred_t = pred + (size_t)t * B * E;

    // staging indexing (conflict-free LDS writes): thread owns (col0,sl0) and (col0+128,sl0)
    const int col0 = (tid & 15) + ((tid >> 6) << 4);   // 0..127
    const int sl0  = (tid >> 4) & 3;                   // 0..3
    const short* g0 = pred_t + (size_t)(ci * 256 + col0) * 256 + sl0 * 8;
    const short* g1 = g0 + (size_t)128 * 256;          // col0+128
    const int l0 = sl0 * 2048 + col0 * 8;              // [sl][col][8] layout
    const int l1 = l0 + 1024;                          // col0+128

    // prologue: issue ALL pred loads (8 eighths x 2 chunks), stage enc, write eighth-0
    s8v RA[8], RB[8];
    #pragma unroll
    for (int ke = 0; ke < 8; ++ke) {
        RA[ke] = *reinterpret_cast<const s8v*>(g0 + ke * 32);
        RB[ke] = *reinterpret_cast<const s8v*>(g1 + ke * 32);
    }
    #pragma unroll
    for (int it = 0; it < 4; ++it) {
        int idx = it * 512 + tid;
        int r = idx >> 5, s = idx & 31;
        const float4* pz = reinterpret_cast<const float4*>(
            z + (size_t)(rb * 64 + r) * S * E + (size_t)(ts + 1 + t) * E + s * 8);
        *reinterpret_cast<s8v*>(encS + r * 256 + ((s ^ (r & 7)) * 8)) = cvt8(pz[0], pz[1]);
    }
    *reinterpret_cast<s8v*>(buf0 + l0) = RA[0];
    *reinterpret_cast<s8v*>(buf0 + l1) = RB[0];
    __syncthreads();

    const int wv = tid >> 6, ln = tid & 63;
    const int wr = wv >> 2, wc = wv & 3;          // 2 row-groups(32) x 4 col-groups(64)
    const int lr = ln & 15, lg = ln >> 4;
    f4v acc[4][2] = {};   // [a: col-tile][b: row-tile]

    #pragma unroll
    for (int ke = 0; ke < 8; ++ke) {
        short* cur = (ke & 1) ? buf1 : buf0;
        short* nxt = (ke & 1) ? buf0 : buf1;
        if (ke < 7) {   // write prefetched eighth ke+1 (registers already loaded)
            *reinterpret_cast<s8v*>(nxt + l0) = RA[ke + 1];
            *reinterpret_cast<s8v*>(nxt + l1) = RB[ke + 1];
        }
        // MFMA on eighth ke
        s8v p[4], e[2];
        #pragma unroll
        for (int a = 0; a < 4; ++a)
            p[a] = *reinterpret_cast<const s8v*>(cur + lg * 2048 + (wc * 64 + a * 16 + lr) * 8);
        #pragma unroll
        for (int b = 0; b < 2; ++b) {
            int er = wr * 32 + b * 16 + lr;
            int sf = ke * 4 + lg;
            e[b] = *reinterpret_cast<const s8v*>(encS + er * 256 + ((sf ^ (er & 7)) * 8));
        }
        #pragma unroll
        for (int a = 0; a < 4; ++a)
            #pragma unroll
            for (int b = 0; b < 2; ++b)
                acc[a][b] = __builtin_amdgcn_mfma_f32_16x16x32_bf16(p[a], e[b], acc[a][b], 0, 0, 0);
        if (ke < 7) __syncthreads();   // last barrier dead: epilogue is LDS-free
    }

    // acc[a][b][i] = score(row = wr*32+b*16+lr, col = ci*256 + wc*64 + a*16 + lg*4 + i)
    #pragma unroll
    for (int b = 0; b < 2; ++b) {
        float sm = 0.0f;
        #pragma unroll
        for (int a = 0; a < 4; ++a)
            #pragma unroll
            for (int i = 0; i < 4; ++i) sm += __expf(acc[a][b][i]);
        sm += __shfl_xor(sm, 16);
        sm += __shfl_xor(sm, 32);
        int rg = rb * 64 + wr * 32 + b * 16 + lr;
        if (lg == 0) atomicAdd(&rowsum[t * B + rg], sm);

        // diagonal element (exactly one lane in one block owns it)
        if ((rg >> 8) == ci) {
            int dl = rg & 255;
            if ((dl >> 6) == wc && ((dl >> 2) & 3) == lg) {
                float dv = 0.0f;
                #pragma unroll
                for (int a = 0; a < 4; ++a)
                    #pragma unroll
                    for (int i = 0; i < 4; ++i)
                        if (((dl >> 4) & 3) == a && (dl & 3) == i) dv = acc[a][b][i];
                diag_g[t * B + rg] = dv;
            }
        }
    }
}

// ---------------- Kernel 3: val = diag - log(rowsum); sum -> out ----------------
__global__ __launch_bounds__(1024) void final_kernel(
    const float* __restrict__ rowsum, const float* __restrict__ diag_g,
    float* __restrict__ out)
{
    int row = blockIdx.x * 1024 + threadIdx.x;   // 0..12287
    float val = diag_g[row] - logf(rowsum[row]);
    #pragma unroll
    for (int o = 1; o < 64; o <<= 1) val += __shfl_xor(val, o);
    __shared__ float red[16];
    int wv = threadIdx.x >> 6, lnn = threadIdx.x & 63;
    if (lnn == 0) red[wv] = val;
    __syncthreads();
    if (threadIdx.x == 0) {
        float tot = 0.0f;
        #pragma unroll
        for (int w = 0; w < 16; ++w) tot += red[w];
        atomicAdd(out, -tot / (float)(B * T));
    }
}

extern "C" void kernel_launch(void* const* d_in, const int* in_sizes, int n_in,
                              void* d_out, int out_size, void* d_ws, size_t ws_size,
                              hipStream_t stream)
{
    (void)in_sizes; (void)n_in; (void)out_size; (void)ws_size;
    const float* z   = (const float*)d_in[0];
    const float* c   = (const float*)d_in[1];
    const float* wkw = (const float*)d_in[2];
    const int*   tsp = (const int*)d_in[4];

    char* w = (char*)d_ws;
    short* pred   = (short*)(w);                 // T*B*E bf16 = 6,291,456 B
    float* rowsum = (float*)(w + 6291456);       // T*B f32 = 49,152 B
    float* diag_g = (float*)(w + 6340608);       // T*B f32 = 49,152 B

    pred_kernel<<<192, 512, 0, stream>>>(c, wkw, tsp, pred, rowsum, (float*)d_out);
    score_kernel<<<768, 512, 0, stream>>>(z, pred, tsp, rowsum, diag_g);
    final_kernel<<<12, 1024, 0, stream>>>(rowsum, diag_g, (float*)d_out);
}

// Round 13
// 28.797 us; speedup vs baseline: 1.1056x; 1.1056x over previous
//
#include <hip/hip_runtime.h>
#include <hip/hip_bf16.h>

constexpr int B = 1024, S = 128, E = 256, C = 256, T = 12;

typedef short s8v __attribute__((ext_vector_type(8)));   // 8 x bf16 bits
typedef float f4v __attribute__((ext_vector_type(4)));

__device__ __forceinline__ short f2bf(float f) {
    unsigned u = __builtin_bit_cast(unsigned, f);
    return (short)((u + 0x7FFFu + ((u >> 16) & 1u)) >> 16);
}
__device__ __forceinline__ s8v cvt8(float4 a, float4 b) {
    s8v o;
    o[0] = f2bf(a.x); o[1] = f2bf(a.y); o[2] = f2bf(a.z); o[3] = f2bf(a.w);
    o[4] = f2bf(b.x); o[5] = f2bf(b.y); o[6] = f2bf(b.z); o[7] = f2bf(b.w);
    return o;
}

// ---------------- Kernel 1: pred[t] = c_last @ Wk_w[t]^T (bias cancels in log-softmax) ----
// R7-proven: 128x128 tiles, 512 threads, f32 in (cvt in staging). Zero-inits rowsum and out.
__global__ __launch_bounds__(512) void pred_kernel(
    const float* __restrict__ c, const float* __restrict__ wkw,
    const int* __restrict__ tsp, short* __restrict__ pred,
    float* __restrict__ rowsum, float* __restrict__ out)
{
    // zero rowsum (12288 floats) + out
    {
        int gi = blockIdx.x * 512 + threadIdx.x;
        if (gi < T * B) rowsum[gi] = 0.0f;
        if (gi == 0) out[0] = 0.0f;
    }
    // bijective XCD swizzle: 192 blocks = 8 xcd * 24; (t,eb) pairs clustered per xcd
    int wgid = blockIdx.x;
    int xcd = wgid & 7, q = wgid >> 3;          // q in 0..23
    int pr = xcd * 3 + (q >> 3);                // 0..23 : (t,eb) pair id
    int bb = q & 7;                              // b-row block (128 rows)
    int t = pr >> 1, eb = pr & 1;                // e-col block (128 cols)
    const int ts = tsp[0];

    __shared__ __align__(16) short AS[128 * 256];   // c_last tile (bf16), 64 KB
    __shared__ __align__(16) short BS[128 * 256];   // wkw tile (bf16), 64 KB
    const int tid = threadIdx.x;

    #pragma unroll
    for (int it = 0; it < 8; ++it) {
        int idx = it * 512 + tid;
        int r = idx >> 5, s = idx & 31;
        const float4* pa = reinterpret_cast<const float4*>(
            c + (size_t)(bb * 128 + r) * S * C + (size_t)ts * C + s * 8);
        *reinterpret_cast<s8v*>(AS + r * 256 + ((s ^ (r & 7)) * 8)) = cvt8(pa[0], pa[1]);
        const float4* pb = reinterpret_cast<const float4*>(
            wkw + ((size_t)t * E + eb * 128 + r) * 256 + s * 8);
        *reinterpret_cast<s8v*>(BS + r * 256 + ((s ^ (r & 7)) * 8)) = cvt8(pb[0], pb[1]);
    }
    __syncthreads();

    const int wv = tid >> 6, ln = tid & 63;
    const int wr = wv >> 2, wc = wv & 3;        // 2 row-groups(64) x 4 col-groups(32)
    const int lr = ln & 15, lg = ln >> 4;
    f4v acc[4][2] = {};

    #pragma unroll
    for (int kk = 0; kk < 8; ++kk) {
        int slot = kk * 4 + lg;
        s8v a[4], b[2];
        #pragma unroll
        for (int m = 0; m < 4; ++m) {
            int r = wr * 64 + m * 16 + lr;
            a[m] = *reinterpret_cast<const s8v*>(AS + r * 256 + ((slot ^ (r & 7)) * 8));
        }
        #pragma unroll
        for (int n = 0; n < 2; ++n) {
            int r = wc * 32 + n * 16 + lr;
            b[n] = *reinterpret_cast<const s8v*>(BS + r * 256 + ((slot ^ (r & 7)) * 8));
        }
        #pragma unroll
        for (int m = 0; m < 4; ++m)
            #pragma unroll
            for (int n = 0; n < 2; ++n)
                acc[m][n] = __builtin_amdgcn_mfma_f32_16x16x32_bf16(a[m], b[n], acc[m][n], 0, 0, 0);
    }

    #pragma unroll
    for (int m = 0; m < 4; ++m)
        #pragma unroll
        for (int n = 0; n < 2; ++n)
            #pragma unroll
            for (int i = 0; i < 4; ++i) {
                int bg = bb * 128 + wr * 64 + m * 16 + lg * 4 + i;   // b row
                int eg = eb * 128 + wc * 32 + n * 16 + lr;           // e col
                pred[(size_t)t * B * E + (size_t)bg * E + eg] = f2bf(acc[m][n][i]);
            }
}

// ---------------- Kernel 2: scores tile + exp-sum partials (no-max) + diag ----------------
// R7 EXACT structure (measured best: 28.8 us): original staging index (4 lanes = 4 slots of
// one col -> 64B-coalesced global reads), 2-deep register prefetch, dbuf LDS eighths.
// ONLY change vs R7: the ke==7 __syncthreads is dropped (epilogue is LDS-free -> dead).
__global__ __launch_bounds__(512) void score_kernel(
    const float* __restrict__ z, const short* __restrict__ pred,
    const int* __restrict__ tsp,
    float* __restrict__ rowsum, float* __restrict__ diag_g)
{
    // bijective swizzle: 768 = 8 xcd * 96; (ci,t) clustered per xcd (pred chunk L2-local)
    int wgid = blockIdx.x;
    int xcd = wgid & 7, q = wgid >> 3;           // q in 0..95
    int pairid = xcd * 6 + (q >> 4);             // 0..47
    int rb = q & 15;                              // enc row-block (64 rows)
    int t = pairid >> 2, ci = pairid & 3;         // col chunk (256 cols)
    const int ts = tsp[0];

    __shared__ __align__(16) char SM[65536];
    short* encS = reinterpret_cast<short*>(SM);              // 64x256 bf16 = 32 KB
    short* buf0 = reinterpret_cast<short*>(SM + 32768);      // pred eighth [4][256][8] = 16 KB
    short* buf1 = reinterpret_cast<short*>(SM + 49152);      // 16 KB

    const int tid = threadIdx.x;
    const short* pred_t = pred + (size_t)t * B * E;

    // per-thread pred chunk addresses: 2 chunks of 16B per eighth (R7 original indexing)
    const int h0 = tid, h1 = tid + 512;
    const int col0 = h0 >> 2, sl0 = h0 & 3;
    const int col1 = h1 >> 2, sl1 = h1 & 3;
    const short* g0 = pred_t + (size_t)(ci * 256 + col0) * 256 + sl0 * 8;
    const short* g1 = pred_t + (size_t)(ci * 256 + col1) * 256 + sl1 * 8;
    const int l0 = sl0 * 2048 + col0 * 8;   // LDS element offsets
    const int l1 = sl1 * 2048 + col1 * 8;

    // prologue: issue eighth-0 loads, stage enc (f32->bf16), write eighth-0, issue eighth-1
    s8v R0 = *reinterpret_cast<const s8v*>(g0);
    s8v R1 = *reinterpret_cast<const s8v*>(g1);
    #pragma unroll
    for (int it = 0; it < 4; ++it) {
        int idx = it * 512 + tid;
        int r = idx >> 5, s = idx & 31;
        const float4* pz = reinterpret_cast<const float4*>(
            z + (size_t)(rb * 64 + r) * S * E + (size_t)(ts + 1 + t) * E + s * 8);
        *reinterpret_cast<s8v*>(encS + r * 256 + ((s ^ (r & 7)) * 8)) = cvt8(pz[0], pz[1]);
    }
    *reinterpret_cast<s8v*>(buf0 + l0) = R0;
    *reinterpret_cast<s8v*>(buf0 + l1) = R1;
    R0 = *reinterpret_cast<const s8v*>(g0 + 32);
    R1 = *reinterpret_cast<const s8v*>(g1 + 32);
    __syncthreads();

    const int wv = tid >> 6, ln = tid & 63;
    const int wr = wv >> 2, wc = wv & 3;          // 2 row-groups(32) x 4 col-groups(64)
    const int lr = ln & 15, lg = ln >> 4;
    f4v acc[4][2] = {};   // [a: col-tile][b: row-tile]

    #pragma unroll
    for (int ke = 0; ke < 8; ++ke) {
        short* cur = (ke & 1) ? buf1 : buf0;
        short* nxt = (ke & 1) ? buf0 : buf1;
        if (ke < 7) {   // write prefetched eighth ke+1
            *reinterpret_cast<s8v*>(nxt + l0) = R0;
            *reinterpret_cast<s8v*>(nxt + l1) = R1;
        }
        if (ke < 6) {   // issue loads for eighth ke+2
            R0 = *reinterpret_cast<const s8v*>(g0 + (ke + 2) * 32);
            R1 = *reinterpret_cast<const s8v*>(g1 + (ke + 2) * 32);
        }
        // MFMA on eighth ke
        s8v p[4], e[2];
        #pragma unroll
        for (int a = 0; a < 4; ++a)
            p[a] = *reinterpret_cast<const s8v*>(cur + lg * 2048 + (wc * 64 + a * 16 + lr) * 8);
        #pragma unroll
        for (int b = 0; b < 2; ++b) {
            int er = wr * 32 + b * 16 + lr;
            int sf = ke * 4 + lg;
            e[b] = *reinterpret_cast<const s8v*>(encS + er * 256 + ((sf ^ (er & 7)) * 8));
        }
        #pragma unroll
        for (int a = 0; a < 4; ++a)
            #pragma unroll
            for (int b = 0; b < 2; ++b)
                acc[a][b] = __builtin_amdgcn_mfma_f32_16x16x32_bf16(p[a], e[b], acc[a][b], 0, 0, 0);
        if (ke < 7) __syncthreads();   // final barrier dead: epilogue is LDS-free
    }

    // acc[a][b][i] = score(row = wr*32+b*16+lr, col = ci*256 + wc*64 + a*16 + lg*4 + i)
    #pragma unroll
    for (int b = 0; b < 2; ++b) {
        float sm = 0.0f;
        #pragma unroll
        for (int a = 0; a < 4; ++a)
            #pragma unroll
            for (int i = 0; i < 4; ++i) sm += __expf(acc[a][b][i]);
        sm += __shfl_xor(sm, 16);
        sm += __shfl_xor(sm, 32);
        int rg = rb * 64 + wr * 32 + b * 16 + lr;
        if (lg == 0) atomicAdd(&rowsum[t * B + rg], sm);

        // diagonal element (exactly one lane in one block owns it)
        if ((rg >> 8) == ci) {
            int dl = rg & 255;
            if ((dl >> 6) == wc && ((dl >> 2) & 3) == lg) {
                float dv = 0.0f;
                #pragma unroll
                for (int a = 0; a < 4; ++a)
                    #pragma unroll
                    for (int i = 0; i < 4; ++i)
                        if (((dl >> 4) & 3) == a && (dl & 3) == i) dv = acc[a][b][i];
                diag_g[t * B + rg] = dv;
            }
        }
    }
}

// ---------------- Kernel 3: val = diag - log(rowsum); sum -> out ----------------
__global__ __launch_bounds__(1024) void final_kernel(
    const float* __restrict__ rowsum, const float* __restrict__ diag_g,
    float* __restrict__ out)
{
    int row = blockIdx.x * 1024 + threadIdx.x;   // 0..12287
    float val = diag_g[row] - logf(rowsum[row]);
    #pragma unroll
    for (int o = 1; o < 64; o <<= 1) val += __shfl_xor(val, o);
    __shared__ float red[16];
    int wv = threadIdx.x >> 6, lnn = threadIdx.x & 63;
    if (lnn == 0) red[wv] = val;
    __syncthreads();
    if (threadIdx.x == 0) {
        float tot = 0.0f;
        #pragma unroll
        for (int w = 0; w < 16; ++w) tot += red[w];
        atomicAdd(out, -tot / (float)(B * T));
    }
}

extern "C" void kernel_launch(void* const* d_in, const int* in_sizes, int n_in,
                              void* d_out, int out_size, void* d_ws, size_t ws_size,
                              hipStream_t stream)
{
    (void)in_sizes; (void)n_in; (void)out_size; (void)ws_size;
    const float* z   = (const float*)d_in[0];
    const float* c   = (const float*)d_in[1];
    const float* wkw = (const float*)d_in[2];
    const int*   tsp = (const int*)d_in[4];

    char* w = (char*)d_ws;
    short* pred   = (short*)(w);                 // T*B*E bf16 = 6,291,456 B
    float* rowsum = (float*)(w + 6291456);       // T*B f32 = 49,152 B
    float* diag_g = (float*)(w + 6340608);       // T*B f32 = 49,152 B

    pred_kernel<<<192, 512, 0, stream>>>(c, wkw, tsp, pred, rowsum, (float*)d_out);
    score_kernel<<<768, 512, 0, stream>>>(z, pred, tsp, rowsum, diag_g);
    final_kernel<<<12, 1024, 0, stream>>>(rowsum, diag_g, (float*)d_out);
}